// Round 1
// baseline (1561.471 us; speedup 1.0000x reference)
//
#include <hip/hip_runtime.h>
#include <math.h>

#define N_NODES 50000
#define N_EDGES 1600000
#define ETOT (N_EDGES + N_NODES)
#define HC 128
#define HEADS 4
#define HID 32
#define NEG_SLOPE 0.2f

// ---------------- CSR build ----------------

__global__ __launch_bounds__(256) void hist_kernel(const int* __restrict__ dstArr, int* __restrict__ deg) {
    int i = blockIdx.x * 256 + threadIdx.x;
    if (i >= ETOT) return;
    int d = (i < N_EDGES) ? dstArr[i] : (i - N_EDGES);
    atomicAdd(&deg[d], 1);
}

__global__ __launch_bounds__(1024) void scan_kernel(const int* __restrict__ deg, int* __restrict__ rowStart) {
    __shared__ int buf[1024];
    __shared__ int carry;
    if (threadIdx.x == 0) carry = 0;
    __syncthreads();
    for (int base = 0; base < N_NODES; base += 1024) {
        int i = base + threadIdx.x;
        int v = (i < N_NODES) ? deg[i] : 0;
        buf[threadIdx.x] = v;
        __syncthreads();
        for (int off = 1; off < 1024; off <<= 1) {
            int t = (threadIdx.x >= off) ? buf[threadIdx.x - off] : 0;
            __syncthreads();
            buf[threadIdx.x] += t;
            __syncthreads();
        }
        int incl = buf[threadIdx.x];
        if (i < N_NODES) rowStart[i] = carry + incl - v;
        __syncthreads();
        if (threadIdx.x == 1023) carry += buf[1023];
        __syncthreads();
    }
    if (threadIdx.x == 0) rowStart[N_NODES] = carry;
}

__global__ __launch_bounds__(256) void scatter_kernel(const int* __restrict__ srcArr, const int* __restrict__ dstArr,
                                                      int* __restrict__ cursor, int* __restrict__ srcS) {
    int i = blockIdx.x * 256 + threadIdx.x;
    if (i >= ETOT) return;
    int s, d;
    if (i < N_EDGES) { s = srcArr[i]; d = dstArr[i]; }
    else             { s = i - N_EDGES; d = s; }
    int pos = atomicAdd(&cursor[d], 1);
    srcS[pos] = s;
}

// ---------------- GEMM: XL = x@Wl + bl, XR = x@Wr + br ----------------
// grid = (ceil(N/64), 4). blockIdx.y selects 64-col tile of [Wl | Wr] (256 cols).

__global__ __launch_bounds__(256) void gemm_kernel(const float* __restrict__ x,
    const float* __restrict__ Wl, const float* __restrict__ bl,
    const float* __restrict__ Wr, const float* __restrict__ br,
    float* __restrict__ XL, float* __restrict__ XR) {
    __shared__ float As[64][68];   // pad 68: 2-way (free) bank aliasing on a-reads
    __shared__ float Bs[64][64];
    int t = threadIdx.x;
    int rb = blockIdx.x * 64;
    int cb = blockIdx.y * 64;
    const float* W; const float* bias; float* out; int c0;
    if (cb < HC) { W = Wl; bias = bl; out = XL; c0 = cb; }
    else         { W = Wr; bias = br; out = XR; c0 = cb - HC; }
    int tx = t & 15, ty = t >> 4;
    float acc[4][4];
#pragma unroll
    for (int i = 0; i < 4; i++)
#pragma unroll
        for (int j = 0; j < 4; j++) acc[i][j] = 0.f;

    for (int kt = 0; kt < 2; kt++) {
#pragma unroll
        for (int it = 0; it < 4; it++) {            // A tile: 64 rows x 64 cols
            int idx = it * 256 + t;
            int r = idx >> 4, f = idx & 15;
            int gr = rb + r;
            float4 v = make_float4(0.f, 0.f, 0.f, 0.f);
            if (gr < N_NODES) v = *reinterpret_cast<const float4*>(&x[gr * HC + kt * 64 + f * 4]);
            *reinterpret_cast<float4*>(&As[r][f * 4]) = v;
        }
#pragma unroll
        for (int it = 0; it < 4; it++) {            // B tile: 64 k-rows x 64 cols
            int idx = it * 256 + t;
            int k = idx >> 4, f = idx & 15;
            float4 v = *reinterpret_cast<const float4*>(&W[(kt * 64 + k) * HC + c0 + f * 4]);
            *reinterpret_cast<float4*>(&Bs[k][f * 4]) = v;
        }
        __syncthreads();
#pragma unroll
        for (int k = 0; k < 64; k++) {
            float a0 = As[ty * 4 + 0][k];
            float a1 = As[ty * 4 + 1][k];
            float a2 = As[ty * 4 + 2][k];
            float a3 = As[ty * 4 + 3][k];
            float4 bv = *reinterpret_cast<const float4*>(&Bs[k][tx * 4]);
            acc[0][0] += a0 * bv.x; acc[0][1] += a0 * bv.y; acc[0][2] += a0 * bv.z; acc[0][3] += a0 * bv.w;
            acc[1][0] += a1 * bv.x; acc[1][1] += a1 * bv.y; acc[1][2] += a1 * bv.z; acc[1][3] += a1 * bv.w;
            acc[2][0] += a2 * bv.x; acc[2][1] += a2 * bv.y; acc[2][2] += a2 * bv.z; acc[2][3] += a2 * bv.w;
            acc[3][0] += a3 * bv.x; acc[3][1] += a3 * bv.y; acc[3][2] += a3 * bv.z; acc[3][3] += a3 * bv.w;
        }
        __syncthreads();
    }
    float4 bb = *reinterpret_cast<const float4*>(&bias[c0 + tx * 4]);
#pragma unroll
    for (int i = 0; i < 4; i++) {
        int gr = rb + ty * 4 + i;
        if (gr < N_NODES) {
            float4 o;
            o.x = acc[i][0] + bb.x; o.y = acc[i][1] + bb.y;
            o.z = acc[i][2] + bb.z; o.w = acc[i][3] + bb.w;
            *reinterpret_cast<float4*>(&out[gr * HC + c0 + tx * 4]) = o;
        }
    }
}

// ---------------- GAT edge scores: one wave per destination node ----------------

__global__ __launch_bounds__(256) void gat_e_kernel(const float* __restrict__ XL, const float* __restrict__ XR,
    const float* __restrict__ att, const int* __restrict__ rowStart, const int* __restrict__ srcS,
    float* __restrict__ EW, float* __restrict__ mArr) {
    int wv = threadIdx.x >> 6;
    int l = threadIdx.x & 63;
    int n = blockIdx.x * 4 + wv;
    if (n >= N_NODES) return;
    int s0 = rowStart[n], s1 = rowStart[n + 1];
    float2 xr2 = *reinterpret_cast<const float2*>(&XR[n * HC + 2 * l]);
    float2 a2  = *reinterpret_cast<const float2*>(&att[2 * l]);
    float mmax = -__builtin_inff();
    for (int p = s0; p < s1; p++) {
        int src = srcS[p];
        float2 xl2 = *reinterpret_cast<const float2*>(&XL[src * HC + 2 * l]);
        float hx = xl2.x + xr2.x;
        float hy = xl2.y + xr2.y;
        hx = hx > 0.f ? hx : NEG_SLOPE * hx;
        hy = hy > 0.f ? hy : NEG_SLOPE * hy;
        float c = a2.x * hx + a2.y * hy;
        c += __shfl_xor(c, 1);
        c += __shfl_xor(c, 2);
        c += __shfl_xor(c, 4);
        c += __shfl_xor(c, 8);      // all 16 lanes of each head group now hold e_h
        if ((l & 15) == 0) EW[p * 4 + (l >> 4)] = c;
        mmax = fmaxf(mmax, c);
    }
    if ((l & 15) == 0) mArr[n * 4 + (l >> 4)] = mmax;
}

// ---------------- GAT aggregate: softmax + weighted sum, one wave per node ----------------

__global__ __launch_bounds__(256) void gat_agg_kernel(const float* __restrict__ XL,
    const float* __restrict__ EW, const float* __restrict__ mArr,
    const int* __restrict__ rowStart, const int* __restrict__ srcS,
    const float* __restrict__ bvec, float* __restrict__ out, int applyElu) {
    int wv = threadIdx.x >> 6;
    int l = threadIdx.x & 63;
    int n = blockIdx.x * 4 + wv;
    if (n >= N_NODES) return;
    int s0 = rowStart[n], s1 = rowStart[n + 1];
    int h = l >> 4;
    float mm = mArr[n * 4 + h];
    float z = 0.f;
    float accx = 0.f, accy = 0.f;
    for (int p = s0; p < s1; p++) {
        int src = srcS[p];
        float e = EW[p * 4 + h];
        float w = __expf(e - mm);
        z += w;
        float2 xl2 = *reinterpret_cast<const float2*>(&XL[src * HC + 2 * l]);
        accx += w * xl2.x;
        accy += w * xl2.y;
    }
    float zinv = 1.f / z;
    float2 b2 = *reinterpret_cast<const float2*>(&bvec[2 * l]);
    float ox = accx * zinv + b2.x;
    float oy = accy * zinv + b2.y;
    if (applyElu) {
        ox = ox > 0.f ? ox : (__expf(ox) - 1.f);
        oy = oy > 0.f ? oy : (__expf(oy) - 1.f);
    }
    *reinterpret_cast<float2*>(&out[n * HC + 2 * l]) = make_float2(ox, oy);
}

// ---------------- launch ----------------

extern "C" void kernel_launch(void* const* d_in, const int* in_sizes, int n_in,
                              void* d_out, int out_size, void* d_ws, size_t ws_size,
                              hipStream_t stream) {
    const float* x = (const float*)d_in[0];
    const int* ei = (const int*)d_in[1];
    const int* srcArr = ei;
    const int* dstArr = ei + N_EDGES;

    char* ws = (char*)d_ws;
    size_t off = 0;
    auto alloc = [&](size_t bytes) -> void* {
        void* p = ws + off;
        off = (off + bytes + 511) & ~(size_t)511;
        return p;
    };
    float* P      = (float*)alloc((size_t)N_NODES * HC * 4);
    float* XL     = (float*)alloc((size_t)N_NODES * HC * 4);
    float* XR     = (float*)alloc((size_t)N_NODES * HC * 4);
    float* EW     = (float*)alloc((size_t)ETOT * HEADS * 4);
    float* mArr   = (float*)alloc((size_t)N_NODES * HEADS * 4);
    int* deg      = (int*)alloc((size_t)N_NODES * 4);
    int* cursor   = (int*)alloc((size_t)N_NODES * 4);
    int* rowStart = (int*)alloc((size_t)(N_NODES + 1) * 4);
    int* srcS     = (int*)alloc((size_t)ETOT * 4);

    hipMemsetAsync(deg, 0, (size_t)N_NODES * 4, stream);
    hist_kernel<<<(ETOT + 255) / 256, 256, 0, stream>>>(dstArr, deg);
    scan_kernel<<<1, 1024, 0, stream>>>(deg, rowStart);
    hipMemcpyAsync(cursor, rowStart, (size_t)N_NODES * 4, hipMemcpyDeviceToDevice, stream);
    scatter_kernel<<<(ETOT + 255) / 256, 256, 0, stream>>>(srcArr, dstArr, cursor, srcS);

    for (int lyr = 0; lyr < 3; lyr++) {
        const float* xin = (lyr == 0) ? x : P;
        float* xout = (lyr == 2) ? (float*)d_out : P;
        const float* Wl  = (const float*)d_in[2 + 6 * lyr + 0];
        const float* bl  = (const float*)d_in[2 + 6 * lyr + 1];
        const float* Wr  = (const float*)d_in[2 + 6 * lyr + 2];
        const float* br  = (const float*)d_in[2 + 6 * lyr + 3];
        const float* att = (const float*)d_in[2 + 6 * lyr + 4];
        const float* bb  = (const float*)d_in[2 + 6 * lyr + 5];

        dim3 ggrid((N_NODES + 63) / 64, 4);
        gemm_kernel<<<ggrid, 256, 0, stream>>>(xin, Wl, bl, Wr, br, XL, XR);

        int nb = (N_NODES + 3) / 4;
        gat_e_kernel<<<nb, 256, 0, stream>>>(XL, XR, att, rowStart, srcS, EW, mArr);
        gat_agg_kernel<<<nb, 256, 0, stream>>>(XL, EW, mArr, rowStart, srcS, bb, xout, lyr < 2 ? 1 : 0);
    }
}

// Round 2
// 843.730 us; speedup vs baseline: 1.8507x; 1.8507x over previous
//
#include <hip/hip_runtime.h>
#include <math.h>

#define N_NODES 50000
#define N_EDGES 1600000
#define ETOT (N_EDGES + N_NODES)
#define HC 128
#define HEADS 4
#define HID 32
#define NEG_SLOPE 0.2f

// ---------------- CSR build ----------------

__global__ __launch_bounds__(256) void hist_kernel(const int* __restrict__ dstArr, int* __restrict__ deg) {
    int i = blockIdx.x * 256 + threadIdx.x;
    if (i >= ETOT) return;
    int d = (i < N_EDGES) ? dstArr[i] : (i - N_EDGES);
    atomicAdd(&deg[d], 1);
}

__global__ __launch_bounds__(1024) void scan_kernel(const int* __restrict__ deg, int* __restrict__ rowStart) {
    __shared__ int buf[1024];
    __shared__ int carry;
    if (threadIdx.x == 0) carry = 0;
    __syncthreads();
    for (int base = 0; base < N_NODES; base += 1024) {
        int i = base + threadIdx.x;
        int v = (i < N_NODES) ? deg[i] : 0;
        buf[threadIdx.x] = v;
        __syncthreads();
        for (int off = 1; off < 1024; off <<= 1) {
            int t = (threadIdx.x >= off) ? buf[threadIdx.x - off] : 0;
            __syncthreads();
            buf[threadIdx.x] += t;
            __syncthreads();
        }
        int incl = buf[threadIdx.x];
        if (i < N_NODES) rowStart[i] = carry + incl - v;
        __syncthreads();
        if (threadIdx.x == 1023) carry += buf[1023];
        __syncthreads();
    }
    if (threadIdx.x == 0) rowStart[N_NODES] = carry;
}

__global__ __launch_bounds__(256) void scatter_kernel(const int* __restrict__ srcArr, const int* __restrict__ dstArr,
                                                      int* __restrict__ cursor, int* __restrict__ srcS) {
    int i = blockIdx.x * 256 + threadIdx.x;
    if (i >= ETOT) return;
    int s, d;
    if (i < N_EDGES) { s = srcArr[i]; d = dstArr[i]; }
    else             { s = i - N_EDGES; d = s; }
    int pos = atomicAdd(&cursor[d], 1);
    srcS[pos] = s;
}

// ---------------- GEMM: XL = x@Wl + bl, XR = x@Wr + br ----------------

__global__ __launch_bounds__(256) void gemm_kernel(const float* __restrict__ x,
    const float* __restrict__ Wl, const float* __restrict__ bl,
    const float* __restrict__ Wr, const float* __restrict__ br,
    float* __restrict__ XL, float* __restrict__ XR) {
    __shared__ float As[64][68];
    __shared__ float Bs[64][64];
    int t = threadIdx.x;
    int rb = blockIdx.x * 64;
    int cb = blockIdx.y * 64;
    const float* W; const float* bias; float* out; int c0;
    if (cb < HC) { W = Wl; bias = bl; out = XL; c0 = cb; }
    else         { W = Wr; bias = br; out = XR; c0 = cb - HC; }
    int tx = t & 15, ty = t >> 4;
    float acc[4][4];
#pragma unroll
    for (int i = 0; i < 4; i++)
#pragma unroll
        for (int j = 0; j < 4; j++) acc[i][j] = 0.f;

    for (int kt = 0; kt < 2; kt++) {
#pragma unroll
        for (int it = 0; it < 4; it++) {
            int idx = it * 256 + t;
            int r = idx >> 4, f = idx & 15;
            int gr = rb + r;
            float4 v = make_float4(0.f, 0.f, 0.f, 0.f);
            if (gr < N_NODES) v = *reinterpret_cast<const float4*>(&x[gr * HC + kt * 64 + f * 4]);
            *reinterpret_cast<float4*>(&As[r][f * 4]) = v;
        }
#pragma unroll
        for (int it = 0; it < 4; it++) {
            int idx = it * 256 + t;
            int k = idx >> 4, f = idx & 15;
            float4 v = *reinterpret_cast<const float4*>(&W[(kt * 64 + k) * HC + c0 + f * 4]);
            *reinterpret_cast<float4*>(&Bs[k][f * 4]) = v;
        }
        __syncthreads();
#pragma unroll
        for (int k = 0; k < 64; k++) {
            float a0 = As[ty * 4 + 0][k];
            float a1 = As[ty * 4 + 1][k];
            float a2 = As[ty * 4 + 2][k];
            float a3 = As[ty * 4 + 3][k];
            float4 bv = *reinterpret_cast<const float4*>(&Bs[k][tx * 4]);
            acc[0][0] += a0 * bv.x; acc[0][1] += a0 * bv.y; acc[0][2] += a0 * bv.z; acc[0][3] += a0 * bv.w;
            acc[1][0] += a1 * bv.x; acc[1][1] += a1 * bv.y; acc[1][2] += a1 * bv.z; acc[1][3] += a1 * bv.w;
            acc[2][0] += a2 * bv.x; acc[2][1] += a2 * bv.y; acc[2][2] += a2 * bv.z; acc[2][3] += a2 * bv.w;
            acc[3][0] += a3 * bv.x; acc[3][1] += a3 * bv.y; acc[3][2] += a3 * bv.z; acc[3][3] += a3 * bv.w;
        }
        __syncthreads();
    }
    float4 bb = *reinterpret_cast<const float4*>(&bias[c0 + tx * 4]);
#pragma unroll
    for (int i = 0; i < 4; i++) {
        int gr = rb + ty * 4 + i;
        if (gr < N_NODES) {
            float4 o;
            o.x = acc[i][0] + bb.x; o.y = acc[i][1] + bb.y;
            o.z = acc[i][2] + bb.z; o.w = acc[i][3] + bb.w;
            *reinterpret_cast<float4*>(&out[gr * HC + c0 + tx * 4]) = o;
        }
    }
}

// ---------------- Fused GAT: online softmax + weighted aggregate, one wave per node ----------------
// Lane l handles channels 2l,2l+1; head = l>>4. Online-softmax state (m,z) is
// uniform within each 16-lane head group; acc is per-lane.

__device__ __forceinline__ float edge_score(float2 xl2, float2 xr2, float2 a2) {
    float hx = xl2.x + xr2.x;
    float hy = xl2.y + xr2.y;
    hx = hx > 0.f ? hx : NEG_SLOPE * hx;
    hy = hy > 0.f ? hy : NEG_SLOPE * hy;
    float c = a2.x * hx + a2.y * hy;
    c += __shfl_xor(c, 1);
    c += __shfl_xor(c, 2);
    c += __shfl_xor(c, 4);
    c += __shfl_xor(c, 8);   // all 16 lanes of the head group hold e_h
    return c;
}

__global__ __launch_bounds__(256) void gat_fused_kernel(const float* __restrict__ XL,
    const float* __restrict__ XR, const float* __restrict__ att,
    const int* __restrict__ rowStart, const int* __restrict__ srcS,
    const float* __restrict__ bvec, float* __restrict__ out, int applyElu) {
    int wv = threadIdx.x >> 6;
    int l = threadIdx.x & 63;
    int n = blockIdx.x * 4 + wv;
    if (n >= N_NODES) return;
    int s0 = rowStart[n], s1 = rowStart[n + 1];
    float2 xr2 = *reinterpret_cast<const float2*>(&XR[n * HC + 2 * l]);
    float2 a2  = *reinterpret_cast<const float2*>(&att[2 * l]);

    float m = -__builtin_inff();
    float z = 0.f, accx = 0.f, accy = 0.f;

    int p = s0;
    for (; p + 2 <= s1; p += 2) {
        // issue both independent load chains up front
        int srcA = srcS[p];
        int srcB = srcS[p + 1];
        float2 xlA = *reinterpret_cast<const float2*>(&XL[srcA * HC + 2 * l]);
        float2 xlB = *reinterpret_cast<const float2*>(&XL[srcB * HC + 2 * l]);
        float cA = edge_score(xlA, xr2, a2);
        float cB = edge_score(xlB, xr2, a2);
        // online update A
        {
            float nm = fmaxf(m, cA);
            float s = __expf(m - nm);
            float w = __expf(cA - nm);
            z = z * s + w;
            accx = accx * s + w * xlA.x;
            accy = accy * s + w * xlA.y;
            m = nm;
        }
        // online update B
        {
            float nm = fmaxf(m, cB);
            float s = __expf(m - nm);
            float w = __expf(cB - nm);
            z = z * s + w;
            accx = accx * s + w * xlB.x;
            accy = accy * s + w * xlB.y;
            m = nm;
        }
    }
    if (p < s1) {
        int src = srcS[p];
        float2 xl2 = *reinterpret_cast<const float2*>(&XL[src * HC + 2 * l]);
        float c = edge_score(xl2, xr2, a2);
        float nm = fmaxf(m, c);
        float s = __expf(m - nm);
        float w = __expf(c - nm);
        z = z * s + w;
        accx = accx * s + w * xl2.x;
        accy = accy * s + w * xl2.y;
        m = nm;
    }

    float zinv = 1.f / z;
    float2 b2 = *reinterpret_cast<const float2*>(&bvec[2 * l]);
    float ox = accx * zinv + b2.x;
    float oy = accy * zinv + b2.y;
    if (applyElu) {
        ox = ox > 0.f ? ox : (__expf(ox) - 1.f);
        oy = oy > 0.f ? oy : (__expf(oy) - 1.f);
    }
    *reinterpret_cast<float2*>(&out[n * HC + 2 * l]) = make_float2(ox, oy);
}

// ---------------- launch ----------------

extern "C" void kernel_launch(void* const* d_in, const int* in_sizes, int n_in,
                              void* d_out, int out_size, void* d_ws, size_t ws_size,
                              hipStream_t stream) {
    const float* x = (const float*)d_in[0];
    const int* ei = (const int*)d_in[1];
    const int* srcArr = ei;
    const int* dstArr = ei + N_EDGES;

    char* ws = (char*)d_ws;
    size_t off = 0;
    auto alloc = [&](size_t bytes) -> void* {
        void* p = ws + off;
        off = (off + bytes + 511) & ~(size_t)511;
        return p;
    };
    float* P      = (float*)alloc((size_t)N_NODES * HC * 4);
    float* XL     = (float*)alloc((size_t)N_NODES * HC * 4);
    float* XR     = (float*)alloc((size_t)N_NODES * HC * 4);
    int* deg      = (int*)alloc((size_t)N_NODES * 4);
    int* cursor   = (int*)alloc((size_t)N_NODES * 4);
    int* rowStart = (int*)alloc((size_t)(N_NODES + 1) * 4);
    int* srcS     = (int*)alloc((size_t)ETOT * 4);

    hipMemsetAsync(deg, 0, (size_t)N_NODES * 4, stream);
    hist_kernel<<<(ETOT + 255) / 256, 256, 0, stream>>>(dstArr, deg);
    scan_kernel<<<1, 1024, 0, stream>>>(deg, rowStart);
    hipMemcpyAsync(cursor, rowStart, (size_t)N_NODES * 4, hipMemcpyDeviceToDevice, stream);
    scatter_kernel<<<(ETOT + 255) / 256, 256, 0, stream>>>(srcArr, dstArr, cursor, srcS);

    for (int lyr = 0; lyr < 3; lyr++) {
        const float* xin = (lyr == 0) ? x : P;
        float* xout = (lyr == 2) ? (float*)d_out : P;
        const float* Wl  = (const float*)d_in[2 + 6 * lyr + 0];
        const float* bl  = (const float*)d_in[2 + 6 * lyr + 1];
        const float* Wr  = (const float*)d_in[2 + 6 * lyr + 2];
        const float* br  = (const float*)d_in[2 + 6 * lyr + 3];
        const float* att = (const float*)d_in[2 + 6 * lyr + 4];
        const float* bb  = (const float*)d_in[2 + 6 * lyr + 5];

        dim3 ggrid((N_NODES + 63) / 64, 4);
        gemm_kernel<<<ggrid, 256, 0, stream>>>(xin, Wl, bl, Wr, br, XL, XR);

        int nb = (N_NODES + 3) / 4;
        gat_fused_kernel<<<nb, 256, 0, stream>>>(XL, XR, att, rowStart, srcS, bb, xout, lyr < 2 ? 1 : 0);
    }
}